// Round 4
// baseline (84.286 us; speedup 1.0000x reference)
//
#include <hip/hip_runtime.h>

// FFMCell combine: out = state * exp((-|a| + i*b) * j) + x, elementwise over
// [T=4096, TRACE=64, CTX=64]; third output = j + i (per-t ints, stored as f32).
// Memory-bound streaming. Lessons: R1 dense-coalesced but only 4 loads in
// flight (latency-limited); R3's adjacent-pair-per-thread halved per-instr
// coalescing density and nt stores inflated WRITE_SIZE +19%. R4: dense
// lane-contiguous float4 per instruction + unroll-2 grid-stride (10 dense
// 16B loads in flight/thread), plain stores.

typedef float f32x4 __attribute__((ext_vector_type(4)));

constexpr int T_DIM = 4096;
constexpr int TRACE = 64;
constexpr int CTX   = 64;
constexpr int N     = T_DIM * TRACE * CTX;   // 16,777,216 elements per array
constexpr int N4    = N / 4;                 // 4,194,304 float4 items

__device__ __forceinline__ void combine4(
    int f4, float tj_pre, int t_pre, bool same_t,
    const float* __restrict__ a, const float* __restrict__ b,
    const float* __restrict__ s_re, const float* __restrict__ s_im,
    const float* __restrict__ x_re, const float* __restrict__ x_im,
    const int* __restrict__ jv,
    float* __restrict__ out)
{
    const int t  = f4 >> 10;           // / (TRACE*CTX/4)
    const int m  = (f4 >> 4) & 63;     // trace index
    const int c4 = (f4 & 15) << 2;     // ctx offset

    const float tj    = (float)jv[t];
    const float decay = __expf(-fabsf(a[m]) * tj);

    const int base = f4 << 2;
    const f32x4 bv = *reinterpret_cast<const f32x4*>(b + c4);
    const f32x4 sr = *reinterpret_cast<const f32x4*>(s_re + base);
    const f32x4 si = *reinterpret_cast<const f32x4*>(s_im + base);
    const f32x4 xr = *reinterpret_cast<const f32x4*>(x_re + base);
    const f32x4 xi = *reinterpret_cast<const f32x4*>(x_im + base);

    f32x4 orv, oiv;
    #pragma unroll
    for (int k = 0; k < 4; ++k) {
        float s, c;
        __sincosf(bv[k] * tj, &s, &c);
        const float gre = decay * c;
        const float gim = decay * s;
        orv[k] = fmaf(sr[k], gre, fmaf(-si[k], gim, xr[k]));
        oiv[k] = fmaf(sr[k], gim, fmaf( si[k], gre, xi[k]));
    }

    *reinterpret_cast<f32x4*>(out + base)     = orv;
    *reinterpret_cast<f32x4*>(out + N + base) = oiv;
}

__global__ __launch_bounds__(256) void ffm_kernel(
    const float* __restrict__ a,
    const float* __restrict__ b,
    const float* __restrict__ s_re,
    const float* __restrict__ s_im,
    const float* __restrict__ x_re,
    const float* __restrict__ x_im,
    const int*   __restrict__ iv,
    const int*   __restrict__ jv,
    float* __restrict__ out)
{
    const int gtid   = blockIdx.x * blockDim.x + threadIdx.x;
    const int stride = gridDim.x * blockDim.x;   // 524288

    // Third output: (j + i) as float, T elements at offset 2*N.
    for (int t = gtid; t < T_DIM; t += stride) {
        out[2 * N + t] = (float)(jv[t] + iv[t]);
    }

    // N4 = 8 * stride exactly: 4 trips of unroll-2, no tail.
    #pragma unroll
    for (int trip = 0; trip < 4; ++trip) {
        const int f4a = gtid + (2 * trip)     * stride;
        const int f4b = gtid + (2 * trip + 1) * stride;
        combine4(f4a, 0.f, 0, false, a, b, s_re, s_im, x_re, x_im, jv, out);
        combine4(f4b, 0.f, 0, false, a, b, s_re, s_im, x_re, x_im, jv, out);
    }
}

extern "C" void kernel_launch(void* const* d_in, const int* in_sizes, int n_in,
                              void* d_out, int out_size, void* d_ws, size_t ws_size,
                              hipStream_t stream) {
    const float* a    = (const float*)d_in[0];
    const float* b    = (const float*)d_in[1];
    const float* s_re = (const float*)d_in[2];
    const float* s_im = (const float*)d_in[3];
    const float* x_re = (const float*)d_in[4];
    const float* x_im = (const float*)d_in[5];
    const int*   iv   = (const int*)d_in[6];
    const int*   jv   = (const int*)d_in[7];
    float* out = (float*)d_out;

    const int block = 256;
    const int grid  = 2048;   // 8 blocks/CU; 32 waves/CU at <=64 VGPR
    ffm_kernel<<<grid, block, 0, stream>>>(a, b, s_re, s_im, x_re, x_im, iv, jv, out);
}

// Round 5
// 81.100 us; speedup vs baseline: 1.0393x; 1.0393x over previous
//
#include <hip/hip_runtime.h>

// FFMCell combine: out = state * exp((-|a| + i*b) * j) + x, elementwise over
// [T=4096, TRACE=64, CTX=64]; third output = j + i (per-t ints, stored as f32).
// Latency/issue-bound, not BW-bound (R1-R4 plateau ~80us; FETCH shows 50% L3
// hits, HBM only ~3 TB/s). R5: hoist loop-invariant b-vector and |a[m]| out of
// the grid-stride loop (stride is a multiple of 4096 elems -> per-thread m,c4
// fixed), and software-pipeline the 4 streaming loads one trip ahead so they
// are in flight during compute+store. launch_bounds(256,8) caps VGPR at 64
// to keep 8 waves/SIMD.

typedef float f32x4 __attribute__((ext_vector_type(4)));

constexpr int T_DIM  = 4096;
constexpr int N      = T_DIM * 64 * 64;      // 16,777,216 elements per array
constexpr int N4     = N / 4;                // 4,194,304 float4 items
constexpr int GRID   = 2048;
constexpr int BLOCK  = 256;
constexpr int STRIDE = GRID * BLOCK;         // 524,288 float4 items
constexpr int TRIPS  = N4 / STRIDE;          // 8, exact
constexpr int T_STEP = STRIDE >> 10;         // 512 t-steps per trip

__global__ __launch_bounds__(BLOCK, 8) void ffm_kernel(
    const float* __restrict__ a,
    const float* __restrict__ b,
    const float* __restrict__ s_re,
    const float* __restrict__ s_im,
    const float* __restrict__ x_re,
    const float* __restrict__ x_im,
    const int*   __restrict__ iv,
    const int*   __restrict__ jv,
    float* __restrict__ out)
{
    const int gtid = blockIdx.x * blockDim.x + threadIdx.x;

    // Third output: (j + i) as float, T elements at offset 2*N.
    if (gtid < T_DIM) {
        out[2 * N + gtid] = (float)(jv[gtid] + iv[gtid]);
    }

    // Per-thread invariants: stride between trips is 512 full t-planes, so
    // the (m, c4) coordinates never change; only t advances by T_STEP.
    const int c4 = (gtid & 15) << 2;       // ctx offset of this float4
    const int m  = (gtid >> 4) & 63;       // trace index
    const int t0 = gtid >> 10;             // starting t (0..511)

    const float am = fabsf(a[m]);
    const f32x4 bv = *reinterpret_cast<const f32x4*>(b + c4);

    int base = gtid << 2;                  // element offset of trip 0

    // Prologue: loads for trip 0.
    f32x4 sr = *reinterpret_cast<const f32x4*>(s_re + base);
    f32x4 si = *reinterpret_cast<const f32x4*>(s_im + base);
    f32x4 xr = *reinterpret_cast<const f32x4*>(x_re + base);
    f32x4 xi = *reinterpret_cast<const f32x4*>(x_im + base);
    float tj = (float)jv[t0];

    #pragma unroll
    for (int trip = 0; trip < TRIPS; ++trip) {
        // Prefetch trip+1 before computing trip (compile-time guarded).
        f32x4 nsr, nsi, nxr, nxi;
        float ntj = 0.f;
        const int nbase = base + (STRIDE << 2);
        if (trip + 1 < TRIPS) {
            nsr = *reinterpret_cast<const f32x4*>(s_re + nbase);
            nsi = *reinterpret_cast<const f32x4*>(s_im + nbase);
            nxr = *reinterpret_cast<const f32x4*>(x_re + nbase);
            nxi = *reinterpret_cast<const f32x4*>(x_im + nbase);
            ntj = (float)jv[t0 + (trip + 1) * T_STEP];
        }

        const float decay = __expf(-am * tj);
        f32x4 orv, oiv;
        #pragma unroll
        for (int k = 0; k < 4; ++k) {
            float s, c;
            __sincosf(bv[k] * tj, &s, &c);
            const float gre = decay * c;
            const float gim = decay * s;
            orv[k] = fmaf(sr[k], gre, fmaf(-si[k], gim, xr[k]));
            oiv[k] = fmaf(sr[k], gim, fmaf( si[k], gre, xi[k]));
        }

        *reinterpret_cast<f32x4*>(out + base)     = orv;
        *reinterpret_cast<f32x4*>(out + N + base) = oiv;

        if (trip + 1 < TRIPS) {
            sr = nsr; si = nsi; xr = nxr; xi = nxi; tj = ntj;
            base = nbase;
        }
    }
}

extern "C" void kernel_launch(void* const* d_in, const int* in_sizes, int n_in,
                              void* d_out, int out_size, void* d_ws, size_t ws_size,
                              hipStream_t stream) {
    const float* a    = (const float*)d_in[0];
    const float* b    = (const float*)d_in[1];
    const float* s_re = (const float*)d_in[2];
    const float* s_im = (const float*)d_in[3];
    const float* x_re = (const float*)d_in[4];
    const float* x_im = (const float*)d_in[5];
    const int*   iv   = (const int*)d_in[6];
    const int*   jv   = (const int*)d_in[7];
    float* out = (float*)d_out;

    ffm_kernel<<<GRID, BLOCK, 0, stream>>>(a, b, s_re, s_im, x_re, x_im, iv, jv, out);
}